// Round 3
// baseline (7790.368 us; speedup 1.0000x reference)
//
#include <hip/hip_runtime.h>

typedef __attribute__((ext_vector_type(8))) short short8;
typedef __attribute__((ext_vector_type(4))) float f32x4;
typedef __attribute__((ext_vector_type(8))) unsigned short ushort8;

__device__ __forceinline__ unsigned short f2bf(float f) {
  union { float f; unsigned u; } v; v.f = f;
  unsigned u = v.u;
  u += 0x7fffu + ((u >> 16) & 1u);
  return (unsigned short)(u >> 16);
}
__device__ __forceinline__ float bf2f(unsigned short u) {
  union { unsigned u; float f; } v; v.u = ((unsigned)u) << 16; return v.f;
}
__device__ __forceinline__ float sigm(float x) { return 1.f / (1.f + __expf(-x)); }
__device__ __forceinline__ float ftanh(float x) { return 1.f - 2.f / (__expf(2.f * x) + 1.f); }
__device__ __forceinline__ short8 as_s8(uint4 v) { union { uint4 u; short8 s; } x; x.u = v; return x.s; }

#define LSTR 40
#define NBLK 512

// ---------------------------------------------------------------------------
// Prep. WcombT_sw: gates weights, fragment-swizzled for 64x32 tiles:
//   [nn=64][kk=25][wnh=2][lane=64][e=8]; n' = nn*32+wnh*16+(l&15) (n'=j*4+gate),
//   k = kk*32+(l>>4)*8+e;  k<257->W_lstm, 288<=k<800->U_lstm, else 0.
// Wk2T_sw: head weights [ni=5][kk=16][wnh=2][nt=2][lane=64][e=8];
//   n = ni*64+wnh*32+nt*16+(l&15): n<256->W_key, 256->W_g, 257..260->W_y.
// WencT row-major (128,1024) for k_enc. Also zero xin/h/z_null/barrier.
// ---------------------------------------------------------------------------
__global__ void k_prep(const float* __restrict__ W_lstm, const float* __restrict__ U_lstm,
                       const float* __restrict__ W_enc, const float* __restrict__ W_key,
                       const float* __restrict__ W_g, const float* __restrict__ W_y,
                       const float* __restrict__ b_key, const float* __restrict__ b_g,
                       const float* __restrict__ b_y,
                       unsigned short* __restrict__ WcombT_sw, unsigned short* __restrict__ Wk2T_sw,
                       unsigned short* __restrict__ WencT, float* __restrict__ bias2,
                       unsigned short* __restrict__ xinA, unsigned short* __restrict__ xinB,
                       float* __restrict__ h, float* __restrict__ z_full, int* __restrict__ bar) {
  const int N1 = 2048 * 800, N2 = 81920, N3 = 128 * 1024, N4 = 320,
            N5 = 512 * 800, N7 = 512 * 512, N8 = 512 * 128;
  int i = blockIdx.x * 256 + threadIdx.x;
  if (i < N1) {
    int nn = i / 25600, rem = i - nn * 25600;
    int kk = rem >> 10, rem2 = rem & 1023;
    int wnh = rem2 >> 9, l = (rem2 >> 3) & 63, e = rem2 & 7;
    int np = nn * 32 + wnh * 16 + (l & 15);
    int k = kk * 32 + (l >> 4) * 8 + e;
    int j = np >> 2, gate = np & 3, n = gate * 512 + j;
    float v = 0.f;
    if (k < 257) v = W_lstm[k * 2048 + n];
    else if (k >= 288) v = U_lstm[(k - 288) * 2048 + n];
    WcombT_sw[i] = f2bf(v);
    return;
  }
  i -= N1;
  if (i < N2) {
    int ni = i / 16384, rem = i - ni * 16384;
    int kk = rem >> 11, rem2 = rem & 2047;
    int wnh = rem2 >> 10, nt = (rem2 >> 9) & 1, l = (rem2 >> 3) & 63, e = rem2 & 7;
    int n = ni * 64 + wnh * 32 + nt * 16 + (l & 15);
    int k = kk * 32 + (l >> 4) * 8 + e;
    float v = 0.f;
    if (n < 256) v = W_key[k * 256 + n];
    else if (n == 256) v = W_g[k];
    else if (n < 261) v = W_y[k * 4 + (n - 257)];
    Wk2T_sw[i] = f2bf(v);
    return;
  }
  i -= N2;
  if (i < N3) {
    int n = i / 1024, k = i - n * 1024;
    WencT[i] = f2bf(W_enc[k * 128 + n]);
    return;
  }
  i -= N3;
  if (i < N4) {
    float v = (i < 256) ? b_key[i] : (i == 256 ? b_g[0] : (i < 261 ? b_y[i - 257] : 0.f));
    bias2[i] = v;
    return;
  }
  i -= N4;
  if (i < N5) { xinA[i] = 0; return; }
  i -= N5;
  if (i < N5) { xinB[i] = 0; return; }
  i -= N5;
  if (i < N7) { h[i] = 0.f; return; }
  i -= N7;
  if (i < N8) {
    int b = i >> 7, z = i & 127;
    z_full[(b * 33 + 32) * 128 + z] = 0.f;
    return;
  }
  i -= N8;
  if (i < 64) bar[i] = 0;
}

// ---------------------------------------------------------------------------
// Encoder GEMM (unchanged from round 2): 44 us, known-good.
// ---------------------------------------------------------------------------
__global__ __launch_bounds__(256) void k_enc(const float* __restrict__ x,
                                             const unsigned short* __restrict__ WencT,
                                             const float* __restrict__ b_enc,
                                             float* __restrict__ zbuf) {
  __shared__ __align__(16) unsigned short As[2][64 * LSTR];
  __shared__ __align__(16) unsigned short Bs[2][128 * LSTR];
  int tid = threadIdx.x;
  int m0 = blockIdx.x * 64;
  int lane = tid & 63, wid = tid >> 6;
  int wm = (wid >> 1) * 32, wn = (wid & 1) * 64;
  int q = lane >> 4, r = lane & 15;
  int ldrowA = tid >> 2, ldcA = (tid & 3) * 8;
  int ldrowB = tid >> 1, ldcB = (tid & 1) * 16;
  const float4* Ag = reinterpret_cast<const float4*>(x + (size_t)(m0 + ldrowA) * 1024);
  const uint4* Bg = reinterpret_cast<const uint4*>(WencT + (size_t)ldrowB * 1024);
  float4 ra0 = Ag[ldcA >> 2], ra1 = Ag[(ldcA >> 2) + 1];
  uint4 rb0 = Bg[ldcB >> 3], rb1 = Bg[(ldcB >> 3) + 1];
  f32x4 acc[2][4] = {};
  int s = 0;
  {
    ushort8 t8;
    t8[0] = f2bf(ra0.x); t8[1] = f2bf(ra0.y); t8[2] = f2bf(ra0.z); t8[3] = f2bf(ra0.w);
    t8[4] = f2bf(ra1.x); t8[5] = f2bf(ra1.y); t8[6] = f2bf(ra1.z); t8[7] = f2bf(ra1.w);
    *reinterpret_cast<ushort8*>(&As[0][ldrowA * LSTR + ldcA]) = t8;
    *reinterpret_cast<uint4*>(&Bs[0][ldrowB * LSTR + ldcB]) = rb0;
    *reinterpret_cast<uint4*>(&Bs[0][ldrowB * LSTR + ldcB + 8]) = rb1;
  }
  __syncthreads();
  for (int kk = 0; kk < 32; ++kk) {
    if (kk < 31) {
      int k0 = (kk + 1) * 32;
      ra0 = Ag[(k0 + ldcA) >> 2]; ra1 = Ag[((k0 + ldcA) >> 2) + 1];
      rb0 = Bg[(k0 + ldcB) >> 3]; rb1 = Bg[((k0 + ldcB) >> 3) + 1];
    }
    short8 a0 = *reinterpret_cast<const short8*>(&As[s][(wm + r) * LSTR + q * 8]);
    short8 a1 = *reinterpret_cast<const short8*>(&As[s][(wm + 16 + r) * LSTR + q * 8]);
#pragma unroll
    for (int nt = 0; nt < 4; ++nt) {
      short8 b0 = *reinterpret_cast<const short8*>(&Bs[s][(wn + nt * 16 + r) * LSTR + q * 8]);
      acc[0][nt] = __builtin_amdgcn_mfma_f32_16x16x32_bf16(a0, b0, acc[0][nt], 0, 0, 0);
      acc[1][nt] = __builtin_amdgcn_mfma_f32_16x16x32_bf16(a1, b0, acc[1][nt], 0, 0, 0);
    }
    if (kk < 31) {
      ushort8 t8;
      t8[0] = f2bf(ra0.x); t8[1] = f2bf(ra0.y); t8[2] = f2bf(ra0.z); t8[3] = f2bf(ra0.w);
      t8[4] = f2bf(ra1.x); t8[5] = f2bf(ra1.y); t8[6] = f2bf(ra1.z); t8[7] = f2bf(ra1.w);
      *reinterpret_cast<ushort8*>(&As[s ^ 1][ldrowA * LSTR + ldcA]) = t8;
      *reinterpret_cast<uint4*>(&Bs[s ^ 1][ldrowB * LSTR + ldcB]) = rb0;
      *reinterpret_cast<uint4*>(&Bs[s ^ 1][ldrowB * LSTR + ldcB + 8]) = rb1;
      s ^= 1;
    }
    __syncthreads();
  }
#pragma unroll
  for (int mt = 0; mt < 2; ++mt)
#pragma unroll
    for (int nt = 0; nt < 4; ++nt)
#pragma unroll
      for (int e = 0; e < 4; ++e) {
        int row = m0 + wm + mt * 16 + q * 4 + e;
        int col = wn + nt * 16 + r;
        zbuf[(size_t)row * 128 + col] = fmaxf(acc[mt][nt][e] + b_enc[col], 0.f);
      }
}

// ---------------------------------------------------------------------------
// LayerNorm over batch axis (unchanged).
// ---------------------------------------------------------------------------
__global__ __launch_bounds__(256) void k_ln(const float* __restrict__ zbuf,
                                            const float* __restrict__ gamma,
                                            const float* __restrict__ beta,
                                            float* __restrict__ z_full) {
  int bid = blockIdx.x;
  int tstep = bid >> 3;
  int z0 = (bid & 7) * 16;
  int tid = threadIdx.x;
  int zl = tid & 15, bg = tid >> 4;
  __shared__ float ps[256], qs[256];
  __shared__ float muS[16], rsS[16];
  float s = 0.f, ss = 0.f;
  for (int ii = 0; ii < 32; ++ii) {
    int b = bg * 32 + ii;
    float v = zbuf[(size_t)(b * 32 + tstep) * 128 + z0 + zl];
    s += v; ss += v * v;
  }
  ps[tid] = s; qs[tid] = ss;
  __syncthreads();
  if (tid < 16) {
    float S = 0.f, Q = 0.f;
    for (int g2 = 0; g2 < 16; ++g2) { S += ps[g2 * 16 + tid]; Q += qs[g2 * 16 + tid]; }
    float mu = S / 512.f;
    float var = Q / 512.f - mu * mu;
    muS[tid] = mu;
    rsS[tid] = rsqrtf(var + 1e-8f);
  }
  __syncthreads();
  float ga = gamma[z0 + zl], be = beta[z0 + zl];
  float mu = muS[zl], rs = rsS[zl];
  for (int ii = 0; ii < 32; ++ii) {
    int b = bg * 32 + ii;
    float v = zbuf[(size_t)(b * 32 + tstep) * 128 + z0 + zl];
    z_full[(size_t)(b * 33 + tstep) * 128 + z0 + zl] = (v - mu) * rs * ga + be;
  }
}

// ---------------------------------------------------------------------------
// Grid barrier: monotonic counter, device-scope atomics, spin bailout.
// ---------------------------------------------------------------------------
__device__ __forceinline__ void gridbar(int* bar, int target) {
  __syncthreads();
  if (threadIdx.x == 0) {
    __threadfence();  // release: writeback this XCD's L2
    __hip_atomic_fetch_add(bar, 1, __ATOMIC_ACQ_REL, __HIP_MEMORY_SCOPE_AGENT);
    long spins = 0;
    while (__hip_atomic_load(bar, __ATOMIC_ACQUIRE, __HIP_MEMORY_SCOPE_AGENT) < target) {
      __builtin_amdgcn_s_sleep(2);
      if (++spins > 20000000L) break;  // fail loudly instead of hanging
    }
  }
  __syncthreads();
  __threadfence();  // acquire: invalidate stale lines before reading remote data
}

// ---------------------------------------------------------------------------
// Persistent recurrence kernel. 512 blocks x 256 threads, 2 blocks/CU.
// Block bid: gates tile nn = bid&63 (32 cols), mi = bid>>6 (64 rows).
// B tile (25600 bf16 = 51.2KB) persistent in LDS all 33 steps.
// Per step: [gates GEMM (barrier-free, direct-global A frags) + cell] BAR
//           [head GEMM (blocks 0..39) + attention (all)] BAR
// ---------------------------------------------------------------------------
__global__ __launch_bounds__(256, 2) void k_coop(
    const unsigned short* __restrict__ WcombT_sw, const unsigned short* __restrict__ Wk2T_sw,
    const float* __restrict__ bias2, const float* __restrict__ b_lstm,
    const float* __restrict__ z_full, const float* __restrict__ cgain,
    const float* __restrict__ cbias, const float* __restrict__ Wg,
    const float* __restrict__ bg,
    unsigned short* xinA, unsigned short* xinB,
    float* h, unsigned short* hbf, unsigned short* Mk,
    float* logits, float* wk_tbl, float* wck_tbl, float* out, int* bar) {
  __shared__ __align__(16) unsigned short Bf[25600];  // 51200 B persistent gates B-tile
  __shared__ __align__(16) char ovl[21504];           // overlay: attnpre / Cs+red4+wkS
  int tid = threadIdx.x;
  int bid = blockIdx.x;
  int l = tid & 63, wid = tid >> 6;
  int q = l >> 4, r = l & 15;
  int wmh = wid >> 1, wnh = wid & 1;
  int wm = wmh * 32;
  int nn = bid & 63, mi = bid >> 6;
  int m0 = mi * 64;
  int ep = 0;

  // --- load persistent gates B tile (fragment-swizzled, contiguous) ---
  {
    const uint2* Bsrc = reinterpret_cast<const uint2*>(WcombT_sw + (size_t)nn * 25600);
    uint2* Bdst = reinterpret_cast<uint2*>(Bf);
#pragma unroll
    for (int i = 0; i < 25; ++i) Bdst[tid + i * 256] = Bsrc[tid + i * 256];
  }

  // --- attention precompute for batch b = bid ---
  {
    float* zs = (float*)ovl;              // 4224 f32
    float* sim = (float*)(ovl + 16896);   // 1089 f32
    const float* zb = z_full + (size_t)bid * 4224;
    for (int i = tid; i < 4224; i += 256) zs[i] = zb[i];
    __syncthreads();
    for (int p = tid; p < 1089; p += 256) {
      int t = p / 33, n = p - t * 33;
      float s = 0.f;
      if (n < t) {
#pragma unroll 8
        for (int k2 = 0; k2 < 128; ++k2) s += zs[t * 128 + k2] * zs[n * 128 + k2];
      }
      sim[p] = s;
    }
    __syncthreads();
    if (tid >= 1 && tid < 33) {
      int t = tid;
      float cg = cgain[0], cb2 = cbias[0];
      float m = -3.0e38f;
      for (int n = 0; n < t; ++n) m = fmaxf(m, sim[t * 33 + n]);
      float ssum = 0.f;
      for (int n = 0; n < t; ++n) ssum += __expf(sim[t * 33 + n] - m);
      float inv = 1.f / ssum;
      float wck = 0.f;
      for (int n = 0; n < t; ++n) {
        float wk = __expf(sim[t * 33 + n] - m) * inv;
        wk_tbl[((size_t)bid * 33 + t) * 33 + n] = wk;
        float ck = 1.f / (1.f + __expf(-(sim[t * 33 + n] * cg + cb2)));
        wck += wk * ck;
      }
      wck_tbl[bid * 33 + t] = wck;
    }
  }
  gridbar(bar, NBLK * ++ep);

  float* Cs = (float*)ovl;                 // 64*33 f32 = 8448 B
  float* red4 = (float*)(ovl + 8448);      // 4 f32
  float* wkS = (float*)(ovl + 8464);       // 33 f32

  for (int t = 0; t < 33; ++t) {
    const unsigned short* cur = (t & 1) ? xinB : xinA;
    unsigned short* nxt = (t & 1) ? xinA : xinB;

    // ---- phase A: gates GEMM (64x32 tile, K=800, barrier-free) ----
    {
      const unsigned short* Arow0 = cur + (size_t)(m0 + wm + r) * 800 + q * 8;
      const unsigned short* Arow1 = Arow0 + 16 * 800;
      uint4 a0p[2], a1p[2];
      a0p[0] = *reinterpret_cast<const uint4*>(Arow0);
      a1p[0] = *reinterpret_cast<const uint4*>(Arow1);
      a0p[1] = *reinterpret_cast<const uint4*>(Arow0 + 32);
      a1p[1] = *reinterpret_cast<const uint4*>(Arow1 + 32);
      f32x4 ac0 = {}, ac1 = {};
#pragma unroll
      for (int kk = 0; kk < 25; ++kk) {
        short8 a0 = as_s8(a0p[kk & 1]), a1 = as_s8(a1p[kk & 1]);
        if (kk + 2 < 25) {
          a0p[kk & 1] = *reinterpret_cast<const uint4*>(Arow0 + (kk + 2) * 32);
          a1p[kk & 1] = *reinterpret_cast<const uint4*>(Arow1 + (kk + 2) * 32);
        }
        short8 bb = *reinterpret_cast<const short8*>(&Bf[kk * 1024 + wnh * 512 + l * 8]);
        ac0 = __builtin_amdgcn_mfma_f32_16x16x32_bf16(a0, bb, ac0, 0, 0, 0);
        ac1 = __builtin_amdgcn_mfma_f32_16x16x32_bf16(a1, bb, ac1, 0, 0, 0);
      }
#pragma unroll
      for (int e = 0; e < 4; ++e) {
        Cs[(wm + q * 4 + e) * 33 + wnh * 16 + r] = ac0[e];
        Cs[(wm + 16 + q * 4 + e) * 33 + wnh * 16 + r] = ac1[e];
      }
      __syncthreads();
      // cell: 64 rows x 8 j's
#pragma unroll
      for (int it = 0; it < 2; ++it) {
        int id = it * 256 + tid;
        int rl = id >> 3, jl = id & 7;
        int j = nn * 8 + jl, brow = m0 + rl;
        float gi = Cs[rl * 33 + jl * 4 + 0] + b_lstm[j];
        float gf = Cs[rl * 33 + jl * 4 + 1] + b_lstm[512 + j];
        float gg = Cs[rl * 33 + jl * 4 + 2] + b_lstm[1024 + j];
        float go = Cs[rl * 33 + jl * 4 + 3] + b_lstm[1536 + j];
        float hold = h[brow * 512 + j];
        float cnew = sigm(gf) * hold + sigm(gi) * ftanh(gg);
        float hnew = sigm(go) * ftanh(cnew);
        h[brow * 512 + j] = hnew;
        hbf[brow * 512 + j] = f2bf(hnew);
        nxt[(size_t)brow * 800 + 288 + j] = f2bf(cnew);
      }
      __syncthreads();
    }
    gridbar(bar, NBLK * ++ep);

    // ---- phase B: head GEMM (blocks 0..39) ----
    if (bid < 40) {
      int mi2 = bid / 5, ni = bid - mi2 * 5;
      int m02 = mi2 * 64, n02 = ni * 64;
      int wm2 = (wid >> 1) * 32, wn2 = (wid & 1) * 32, wnh2 = wid & 1;
      const unsigned short* A0 = hbf + (size_t)(m02 + wm2 + r) * 512 + q * 8;
      const unsigned short* A1 = A0 + 16 * 512;
      const unsigned short* B0 = Wk2T_sw + (size_t)ni * 16384 + wnh2 * 1024 + l * 8;
      uint4 a0p[2], a1p[2], b0p[2], b1p[2];
      a0p[0] = *reinterpret_cast<const uint4*>(A0);
      a1p[0] = *reinterpret_cast<const uint4*>(A1);
      b0p[0] = *reinterpret_cast<const uint4*>(B0);
      b1p[0] = *reinterpret_cast<const uint4*>(B0 + 512);
      a0p[1] = *reinterpret_cast<const uint4*>(A0 + 32);
      a1p[1] = *reinterpret_cast<const uint4*>(A1 + 32);
      b0p[1] = *reinterpret_cast<const uint4*>(B0 + 2048);
      b1p[1] = *reinterpret_cast<const uint4*>(B0 + 2048 + 512);
      f32x4 acc2[2][2] = {};
#pragma unroll
      for (int kk = 0; kk < 16; ++kk) {
        short8 a0 = as_s8(a0p[kk & 1]), a1 = as_s8(a1p[kk & 1]);
        short8 b0 = as_s8(b0p[kk & 1]), b1 = as_s8(b1p[kk & 1]);
        if (kk + 2 < 16) {
          a0p[kk & 1] = *reinterpret_cast<const uint4*>(A0 + (kk + 2) * 32);
          a1p[kk & 1] = *reinterpret_cast<const uint4*>(A1 + (kk + 2) * 32);
          b0p[kk & 1] = *reinterpret_cast<const uint4*>(B0 + (kk + 2) * 2048);
          b1p[kk & 1] = *reinterpret_cast<const uint4*>(B0 + (kk + 2) * 2048 + 512);
        }
        acc2[0][0] = __builtin_amdgcn_mfma_f32_16x16x32_bf16(a0, b0, acc2[0][0], 0, 0, 0);
        acc2[0][1] = __builtin_amdgcn_mfma_f32_16x16x32_bf16(a0, b1, acc2[0][1], 0, 0, 0);
        acc2[1][0] = __builtin_amdgcn_mfma_f32_16x16x32_bf16(a1, b0, acc2[1][0], 0, 0, 0);
        acc2[1][1] = __builtin_amdgcn_mfma_f32_16x16x32_bf16(a1, b1, acc2[1][1], 0, 0, 0);
      }
#pragma unroll
      for (int mt = 0; mt < 2; ++mt)
#pragma unroll
        for (int nt = 0; nt < 2; ++nt)
#pragma unroll
          for (int e = 0; e < 4; ++e) {
            int row = m02 + wm2 + mt * 16 + q * 4 + e;
            int np = n02 + wn2 + nt * 16 + r;
            float v = acc2[mt][nt][e] + bias2[np];
            if (np < 256) Mk[((size_t)row * 33 + t) * 256 + np] = f2bf(fmaxf(v, 0.f));
            else if (np >= 257 && np < 261) logits[row * 4 + (np - 257)] = v;
          }
    }
    // ---- phase B: attention read for batch b = bid ----
    if (t > 0 && t < 32) {
      int b = bid;
      float s = h[b * 512 + tid] * Wg[tid] + h[b * 512 + 256 + tid] * Wg[256 + tid];
#pragma unroll
      for (int off = 1; off < 64; off <<= 1) s += __shfl_xor(s, off);
      if ((tid & 63) == 0) red4[tid >> 6] = s;
      if (tid < t) wkS[tid] = wk_tbl[((size_t)b * 33 + t) * 33 + tid];
      __syncthreads();
      float g = sigm(red4[0] + red4[1] + red4[2] + red4[3] + bg[0]);
      float acc = 0.f;
      for (int n = 0; n < t; ++n) acc += wkS[n] * bf2f(Mk[((size_t)b * 33 + n) * 256 + tid]);
      nxt[(size_t)b * 800 + tid] = f2bf(g * acc);
      if (tid == 0) nxt[(size_t)b * 800 + 256] = f2bf(g * wck_tbl[b * 33 + t]);
      __syncthreads();
    }
    gridbar(bar, NBLK * ++ep);
  }

  // ---- softmax epilogue (block 0) ----
  if (bid == 0) {
    for (int r2 = tid; r2 < 512; r2 += 256) {
      float a = logits[r2 * 4], b = logits[r2 * 4 + 1], c = logits[r2 * 4 + 2], d = logits[r2 * 4 + 3];
      float m = fmaxf(fmaxf(a, b), fmaxf(c, d));
      float ea = __expf(a - m), eb = __expf(b - m), ec = __expf(c - m), ed = __expf(d - m);
      float s = ea + eb + ec + ed;
      out[r2 * 4] = ea / s; out[r2 * 4 + 1] = eb / s;
      out[r2 * 4 + 2] = ec / s; out[r2 * 4 + 3] = ed / s;
    }
  }
}

extern "C" void kernel_launch(void* const* d_in, const int* in_sizes, int n_in,
                              void* d_out, int out_size, void* d_ws, size_t ws_size,
                              hipStream_t stream) {
  const float* x_seq = (const float*)d_in[0];
  const float* W_enc = (const float*)d_in[1];
  const float* b_enc = (const float*)d_in[2];
  const float* W_lstm = (const float*)d_in[3];
  const float* U_lstm = (const float*)d_in[4];
  const float* b_lstm = (const float*)d_in[5];
  const float* W_key = (const float*)d_in[6];
  const float* b_key = (const float*)d_in[7];
  const float* W_g = (const float*)d_in[8];
  const float* b_g = (const float*)d_in[9];
  const float* W_y = (const float*)d_in[10];
  const float* b_y = (const float*)d_in[11];
  const float* gamma = (const float*)d_in[12];
  const float* beta = (const float*)d_in[13];
  const float* cg = (const float*)d_in[14];
  const float* cb = (const float*)d_in[15];

  char* p = (char*)d_ws;
  auto alloc = [&](size_t bytes) {
    char* r = p;
    p += (bytes + 255) & ~(size_t)255;
    return r;
  };
  float* zbuf = (float*)alloc((size_t)16384 * 128 * 4);
  float* z_full = (float*)alloc((size_t)512 * 33 * 128 * 4);
  unsigned short* WcombT_sw = (unsigned short*)alloc((size_t)2048 * 800 * 2);
  unsigned short* WencT = (unsigned short*)alloc((size_t)128 * 1024 * 2);
  unsigned short* Wk2T_sw = (unsigned short*)alloc((size_t)81920 * 2);
  float* bias2 = (float*)alloc(320 * 4);
  unsigned short* xinA = (unsigned short*)alloc((size_t)512 * 800 * 2);
  unsigned short* xinB = (unsigned short*)alloc((size_t)512 * 800 * 2);
  float* h = (float*)alloc((size_t)512 * 512 * 4);
  unsigned short* hbf = (unsigned short*)alloc((size_t)512 * 512 * 2);
  unsigned short* Mk = (unsigned short*)alloc((size_t)512 * 33 * 256 * 2);
  float* logits = (float*)alloc((size_t)512 * 4 * 4);
  float* wk_tbl = (float*)alloc((size_t)512 * 33 * 33 * 4);
  float* wck_tbl = (float*)alloc((size_t)512 * 33 * 4);
  int* bar = (int*)alloc(64 * 4);

  const int prep_total = 2048 * 800 + 81920 + 128 * 1024 + 320 + 2 * 512 * 800 + 512 * 512 + 512 * 128 + 64;
  k_prep<<<(prep_total + 255) / 256, 256, 0, stream>>>(
      W_lstm, U_lstm, W_enc, W_key, W_g, W_y, b_key, b_g, b_y,
      WcombT_sw, Wk2T_sw, WencT, bias2, xinA, xinB, h, z_full, bar);
  k_enc<<<256, 256, 0, stream>>>(x_seq, WencT, b_enc, zbuf);
  k_ln<<<256, 256, 0, stream>>>(zbuf, gamma, beta, z_full);
  k_coop<<<NBLK, 256, 0, stream>>>(WcombT_sw, Wk2T_sw, bias2, b_lstm, z_full,
                                   cg, cb, W_g, b_g, xinA, xinB, h, hbf, Mk,
                                   logits, wk_tbl, wck_tbl, (float*)d_out, bar);
}

// Round 4
// 3929.159 us; speedup vs baseline: 1.9827x; 1.9827x over previous
//
#include <hip/hip_runtime.h>

typedef __attribute__((ext_vector_type(8))) short short8;
typedef __attribute__((ext_vector_type(4))) float f32x4;
typedef __attribute__((ext_vector_type(8))) unsigned short ushort8;

__device__ __forceinline__ unsigned short f2bf(float f) {
  union { float f; unsigned u; } v; v.f = f;
  unsigned u = v.u;
  u += 0x7fffu + ((u >> 16) & 1u);
  return (unsigned short)(u >> 16);
}
__device__ __forceinline__ float bf2f(unsigned short u) {
  union { unsigned u; float f; } v; v.u = ((unsigned)u) << 16; return v.f;
}
__device__ __forceinline__ float sigm(float x) { return 1.f / (1.f + __expf(-x)); }
__device__ __forceinline__ float ftanh(float x) { return 1.f - 2.f / (__expf(2.f * x) + 1.f); }
__device__ __forceinline__ short8 as_s8(uint4 v) { union { uint4 u; short8 s; } x; x.u = v; return x.s; }

#define LSTR 40
#define NBLK 512

// ---------------------------------------------------------------------------
// Prep (same as round 3) + zero 1024-int barrier area.
// ---------------------------------------------------------------------------
__global__ void k_prep(const float* __restrict__ W_lstm, const float* __restrict__ U_lstm,
                       const float* __restrict__ W_enc, const float* __restrict__ W_key,
                       const float* __restrict__ W_g, const float* __restrict__ W_y,
                       const float* __restrict__ b_key, const float* __restrict__ b_g,
                       const float* __restrict__ b_y,
                       unsigned short* __restrict__ WcombT_sw, unsigned short* __restrict__ Wk2T_sw,
                       unsigned short* __restrict__ WencT, float* __restrict__ bias2,
                       unsigned short* __restrict__ xinA, unsigned short* __restrict__ xinB,
                       float* __restrict__ h, float* __restrict__ z_full, int* __restrict__ bar) {
  const int N1 = 2048 * 800, N2 = 81920, N3 = 128 * 1024, N4 = 320,
            N5 = 512 * 800, N7 = 512 * 512, N8 = 512 * 128;
  int i = blockIdx.x * 256 + threadIdx.x;
  if (i < N1) {
    int nn = i / 25600, rem = i - nn * 25600;
    int kk = rem >> 10, rem2 = rem & 1023;
    int wnh = rem2 >> 9, l = (rem2 >> 3) & 63, e = rem2 & 7;
    int np = nn * 32 + wnh * 16 + (l & 15);
    int k = kk * 32 + (l >> 4) * 8 + e;
    int j = np >> 2, gate = np & 3, n = gate * 512 + j;
    float v = 0.f;
    if (k < 257) v = W_lstm[k * 2048 + n];
    else if (k >= 288) v = U_lstm[(k - 288) * 2048 + n];
    WcombT_sw[i] = f2bf(v);
    return;
  }
  i -= N1;
  if (i < N2) {
    int ni = i / 16384, rem = i - ni * 16384;
    int kk = rem >> 11, rem2 = rem & 2047;
    int wnh = rem2 >> 10, nt = (rem2 >> 9) & 1, l = (rem2 >> 3) & 63, e = rem2 & 7;
    int n = ni * 64 + wnh * 32 + nt * 16 + (l & 15);
    int k = kk * 32 + (l >> 4) * 8 + e;
    float v = 0.f;
    if (n < 256) v = W_key[k * 256 + n];
    else if (n == 256) v = W_g[k];
    else if (n < 261) v = W_y[k * 4 + (n - 257)];
    Wk2T_sw[i] = f2bf(v);
    return;
  }
  i -= N2;
  if (i < N3) {
    int n = i / 1024, k = i - n * 1024;
    WencT[i] = f2bf(W_enc[k * 128 + n]);
    return;
  }
  i -= N3;
  if (i < N4) {
    float v = (i < 256) ? b_key[i] : (i == 256 ? b_g[0] : (i < 261 ? b_y[i - 257] : 0.f));
    bias2[i] = v;
    return;
  }
  i -= N4;
  if (i < N5) { xinA[i] = 0; return; }
  i -= N5;
  if (i < N5) { xinB[i] = 0; return; }
  i -= N5;
  if (i < N7) { h[i] = 0.f; return; }
  i -= N7;
  if (i < N8) {
    int b = i >> 7, z = i & 127;
    z_full[(b * 33 + 32) * 128 + z] = 0.f;
    return;
  }
  i -= N8;
  if (i < 1024) bar[i] = 0;
}

// ---------------------------------------------------------------------------
// Encoder GEMM (unchanged, known-good).
// ---------------------------------------------------------------------------
__global__ __launch_bounds__(256) void k_enc(const float* __restrict__ x,
                                             const unsigned short* __restrict__ WencT,
                                             const float* __restrict__ b_enc,
                                             float* __restrict__ zbuf) {
  __shared__ __align__(16) unsigned short As[2][64 * LSTR];
  __shared__ __align__(16) unsigned short Bs[2][128 * LSTR];
  int tid = threadIdx.x;
  int m0 = blockIdx.x * 64;
  int lane = tid & 63, wid = tid >> 6;
  int wm = (wid >> 1) * 32, wn = (wid & 1) * 64;
  int q = lane >> 4, r = lane & 15;
  int ldrowA = tid >> 2, ldcA = (tid & 3) * 8;
  int ldrowB = tid >> 1, ldcB = (tid & 1) * 16;
  const float4* Ag = reinterpret_cast<const float4*>(x + (size_t)(m0 + ldrowA) * 1024);
  const uint4* Bg = reinterpret_cast<const uint4*>(WencT + (size_t)ldrowB * 1024);
  float4 ra0 = Ag[ldcA >> 2], ra1 = Ag[(ldcA >> 2) + 1];
  uint4 rb0 = Bg[ldcB >> 3], rb1 = Bg[(ldcB >> 3) + 1];
  f32x4 acc[2][4] = {};
  int s = 0;
  {
    ushort8 t8;
    t8[0] = f2bf(ra0.x); t8[1] = f2bf(ra0.y); t8[2] = f2bf(ra0.z); t8[3] = f2bf(ra0.w);
    t8[4] = f2bf(ra1.x); t8[5] = f2bf(ra1.y); t8[6] = f2bf(ra1.z); t8[7] = f2bf(ra1.w);
    *reinterpret_cast<ushort8*>(&As[0][ldrowA * LSTR + ldcA]) = t8;
    *reinterpret_cast<uint4*>(&Bs[0][ldrowB * LSTR + ldcB]) = rb0;
    *reinterpret_cast<uint4*>(&Bs[0][ldrowB * LSTR + ldcB + 8]) = rb1;
  }
  __syncthreads();
  for (int kk = 0; kk < 32; ++kk) {
    if (kk < 31) {
      int k0 = (kk + 1) * 32;
      ra0 = Ag[(k0 + ldcA) >> 2]; ra1 = Ag[((k0 + ldcA) >> 2) + 1];
      rb0 = Bg[(k0 + ldcB) >> 3]; rb1 = Bg[((k0 + ldcB) >> 3) + 1];
    }
    short8 a0 = *reinterpret_cast<const short8*>(&As[s][(wm + r) * LSTR + q * 8]);
    short8 a1 = *reinterpret_cast<const short8*>(&As[s][(wm + 16 + r) * LSTR + q * 8]);
#pragma unroll
    for (int nt = 0; nt < 4; ++nt) {
      short8 b0 = *reinterpret_cast<const short8*>(&Bs[s][(wn + nt * 16 + r) * LSTR + q * 8]);
      acc[0][nt] = __builtin_amdgcn_mfma_f32_16x16x32_bf16(a0, b0, acc[0][nt], 0, 0, 0);
      acc[1][nt] = __builtin_amdgcn_mfma_f32_16x16x32_bf16(a1, b0, acc[1][nt], 0, 0, 0);
    }
    if (kk < 31) {
      ushort8 t8;
      t8[0] = f2bf(ra0.x); t8[1] = f2bf(ra0.y); t8[2] = f2bf(ra0.z); t8[3] = f2bf(ra0.w);
      t8[4] = f2bf(ra1.x); t8[5] = f2bf(ra1.y); t8[6] = f2bf(ra1.z); t8[7] = f2bf(ra1.w);
      *reinterpret_cast<ushort8*>(&As[s ^ 1][ldrowA * LSTR + ldcA]) = t8;
      *reinterpret_cast<uint4*>(&Bs[s ^ 1][ldrowB * LSTR + ldcB]) = rb0;
      *reinterpret_cast<uint4*>(&Bs[s ^ 1][ldrowB * LSTR + ldcB + 8]) = rb1;
      s ^= 1;
    }
    __syncthreads();
  }
#pragma unroll
  for (int mt = 0; mt < 2; ++mt)
#pragma unroll
    for (int nt = 0; nt < 4; ++nt)
#pragma unroll
      for (int e = 0; e < 4; ++e) {
        int row = m0 + wm + mt * 16 + q * 4 + e;
        int col = wn + nt * 16 + r;
        zbuf[(size_t)row * 128 + col] = fmaxf(acc[mt][nt][e] + b_enc[col], 0.f);
      }
}

// ---------------------------------------------------------------------------
// LayerNorm over batch axis (unchanged).
// ---------------------------------------------------------------------------
__global__ __launch_bounds__(256) void k_ln(const float* __restrict__ zbuf,
                                            const float* __restrict__ gamma,
                                            const float* __restrict__ beta,
                                            float* __restrict__ z_full) {
  int bid = blockIdx.x;
  int tstep = bid >> 3;
  int z0 = (bid & 7) * 16;
  int tid = threadIdx.x;
  int zl = tid & 15, bg = tid >> 4;
  __shared__ float ps[256], qs[256];
  __shared__ float muS[16], rsS[16];
  float s = 0.f, ss = 0.f;
  for (int ii = 0; ii < 32; ++ii) {
    int b = bg * 32 + ii;
    float v = zbuf[(size_t)(b * 32 + tstep) * 128 + z0 + zl];
    s += v; ss += v * v;
  }
  ps[tid] = s; qs[tid] = ss;
  __syncthreads();
  if (tid < 16) {
    float S = 0.f, Q = 0.f;
    for (int g2 = 0; g2 < 16; ++g2) { S += ps[g2 * 16 + tid]; Q += qs[g2 * 16 + tid]; }
    float mu = S / 512.f;
    float var = Q / 512.f - mu * mu;
    muS[tid] = mu;
    rsS[tid] = rsqrtf(var + 1e-8f);
  }
  __syncthreads();
  float ga = gamma[z0 + zl], be = beta[z0 + zl];
  float mu = muS[zl], rs = rsS[zl];
  for (int ii = 0; ii < 32; ++ii) {
    int b = bg * 32 + ii;
    float v = zbuf[(size_t)(b * 32 + tstep) * 128 + z0 + zl];
    z_full[(size_t)(b * 33 + tstep) * 128 + z0 + zl] = (v - mu) * rs * ga + be;
  }
}

// ---------------------------------------------------------------------------
// Grid barrier v2: per-block flag store (relaxed, no RMW), block 0 aggregates,
// relaxed release poll. Exactly ONE threadfence pair per phase, never per poll.
// bar[0..511] = arrival flags, bar[512] = release counter (monotonic epoch).
// ---------------------------------------------------------------------------
#define SPIN_CAP 50000000L
__device__ __forceinline__ void arrive_wait(int* __restrict__ bar, int ep) {
  int tid = threadIdx.x;
  __syncthreads();  // all block stores drained (vmcnt0 before s_barrier)
  if (tid == 0) {
    __threadfence();  // one buffer_wbl2: push this XCD's L2 to IF$
    __hip_atomic_store(&bar[blockIdx.x], ep, __ATOMIC_RELAXED, __HIP_MEMORY_SCOPE_AGENT);
  }
  if (blockIdx.x == 0) {
    long sp = 0;
    while (__hip_atomic_load(&bar[tid], __ATOMIC_RELAXED, __HIP_MEMORY_SCOPE_AGENT) < ep) {
      __builtin_amdgcn_s_sleep(1);
      if (++sp > SPIN_CAP) break;
    }
    while (__hip_atomic_load(&bar[tid + 256], __ATOMIC_RELAXED, __HIP_MEMORY_SCOPE_AGENT) < ep) {
      __builtin_amdgcn_s_sleep(1);
      if (++sp > SPIN_CAP) break;
    }
    __syncthreads();
    if (tid == 0)
      __hip_atomic_store(&bar[512], ep, __ATOMIC_RELAXED, __HIP_MEMORY_SCOPE_AGENT);
  }
  if (tid == 0) {
    long sp = 0;
    while (__hip_atomic_load(&bar[512], __ATOMIC_RELAXED, __HIP_MEMORY_SCOPE_AGENT) < ep) {
      __builtin_amdgcn_s_sleep(1);
      if (++sp > SPIN_CAP) break;
    }
  }
  __syncthreads();
  __threadfence();  // acquire side: invalidate L1/L2 so remote writes are visible
}

// ---------------------------------------------------------------------------
// Persistent recurrence kernel (structure identical to round 3; new barrier).
// ---------------------------------------------------------------------------
__global__ __launch_bounds__(256, 2) void k_coop(
    const unsigned short* __restrict__ WcombT_sw, const unsigned short* __restrict__ Wk2T_sw,
    const float* __restrict__ bias2, const float* __restrict__ b_lstm,
    const float* __restrict__ z_full, const float* __restrict__ cgain,
    const float* __restrict__ cbias, const float* __restrict__ Wg,
    const float* __restrict__ bg,
    unsigned short* xinA, unsigned short* xinB,
    float* h, unsigned short* hbf, unsigned short* Mk,
    float* logits, float* wk_tbl, float* wck_tbl, float* out, int* bar) {
  __shared__ __align__(16) unsigned short Bf[25600];  // persistent gates B-tile (51.2 KB)
  __shared__ __align__(16) char ovl[21504];           // overlay: attnpre / Cs+red4+wkS
  int tid = threadIdx.x;
  int bid = blockIdx.x;
  int l = tid & 63, wid = tid >> 6;
  int q = l >> 4, r = l & 15;
  int wnh = wid & 1;
  int wm = (wid >> 1) * 32;
  int nn = bid & 63, mi = bid >> 6;
  int m0 = mi * 64;
  int ep = 0;

  // --- load persistent gates B tile ---
  {
    const uint2* Bsrc = reinterpret_cast<const uint2*>(WcombT_sw + (size_t)nn * 25600);
    uint2* Bdst = reinterpret_cast<uint2*>(Bf);
#pragma unroll
    for (int i = 0; i < 25; ++i) Bdst[tid + i * 256] = Bsrc[tid + i * 256];
  }

  // --- attention precompute for batch b = bid (consumed only by this block) ---
  {
    float* zs = (float*)ovl;
    float* sim = (float*)(ovl + 16896);
    const float* zb = z_full + (size_t)bid * 4224;
    for (int i = tid; i < 4224; i += 256) zs[i] = zb[i];
    __syncthreads();
    for (int p = tid; p < 1089; p += 256) {
      int t = p / 33, n = p - t * 33;
      float s = 0.f;
      if (n < t) {
#pragma unroll 8
        for (int k2 = 0; k2 < 128; ++k2) s += zs[t * 128 + k2] * zs[n * 128 + k2];
      }
      sim[p] = s;
    }
    __syncthreads();
    if (tid >= 1 && tid < 33) {
      int t = tid;
      float cg = cgain[0], cb2 = cbias[0];
      float m = -3.0e38f;
      for (int n = 0; n < t; ++n) m = fmaxf(m, sim[t * 33 + n]);
      float ssum = 0.f;
      for (int n = 0; n < t; ++n) ssum += __expf(sim[t * 33 + n] - m);
      float inv = 1.f / ssum;
      float wck = 0.f;
      for (int n = 0; n < t; ++n) {
        float wk = __expf(sim[t * 33 + n] - m) * inv;
        wk_tbl[((size_t)bid * 33 + t) * 33 + n] = wk;
        float ck = 1.f / (1.f + __expf(-(sim[t * 33 + n] * cg + cb2)));
        wck += wk * ck;
      }
      wck_tbl[bid * 33 + t] = wck;
    }
  }
  __syncthreads();  // protect ovl reuse (no grid barrier needed here)

  float* Cs = (float*)ovl;
  float* red4 = (float*)(ovl + 8448);
  float* wkS = (float*)(ovl + 8464);

  for (int t = 0; t < 33; ++t) {
    const unsigned short* cur = (t & 1) ? xinB : xinA;
    unsigned short* nxt = (t & 1) ? xinA : xinB;

    // ---- phase A: gates GEMM (64x32 tile, K=800) + fused cell ----
    {
      const unsigned short* Arow0 = cur + (size_t)(m0 + wm + r) * 800 + q * 8;
      const unsigned short* Arow1 = Arow0 + 16 * 800;
      uint4 a0p[2], a1p[2];
      a0p[0] = *reinterpret_cast<const uint4*>(Arow0);
      a1p[0] = *reinterpret_cast<const uint4*>(Arow1);
      a0p[1] = *reinterpret_cast<const uint4*>(Arow0 + 32);
      a1p[1] = *reinterpret_cast<const uint4*>(Arow1 + 32);
      f32x4 ac0 = {}, ac1 = {};
#pragma unroll
      for (int kk = 0; kk < 25; ++kk) {
        short8 a0 = as_s8(a0p[kk & 1]), a1 = as_s8(a1p[kk & 1]);
        if (kk + 2 < 25) {
          a0p[kk & 1] = *reinterpret_cast<const uint4*>(Arow0 + (kk + 2) * 32);
          a1p[kk & 1] = *reinterpret_cast<const uint4*>(Arow1 + (kk + 2) * 32);
        }
        short8 bb = *reinterpret_cast<const short8*>(&Bf[kk * 1024 + wnh * 512 + l * 8]);
        ac0 = __builtin_amdgcn_mfma_f32_16x16x32_bf16(a0, bb, ac0, 0, 0, 0);
        ac1 = __builtin_amdgcn_mfma_f32_16x16x32_bf16(a1, bb, ac1, 0, 0, 0);
      }
#pragma unroll
      for (int e = 0; e < 4; ++e) {
        Cs[(wm + q * 4 + e) * 33 + wnh * 16 + r] = ac0[e];
        Cs[(wm + 16 + q * 4 + e) * 33 + wnh * 16 + r] = ac1[e];
      }
      __syncthreads();
#pragma unroll
      for (int it = 0; it < 2; ++it) {
        int id = it * 256 + tid;
        int rl = id >> 3, jl = id & 7;
        int j = nn * 8 + jl, brow = m0 + rl;
        float gi = Cs[rl * 33 + jl * 4 + 0] + b_lstm[j];
        float gf = Cs[rl * 33 + jl * 4 + 1] + b_lstm[512 + j];
        float gg = Cs[rl * 33 + jl * 4 + 2] + b_lstm[1024 + j];
        float go = Cs[rl * 33 + jl * 4 + 3] + b_lstm[1536 + j];
        float hold = h[brow * 512 + j];
        float cnew = sigm(gf) * hold + sigm(gi) * ftanh(gg);
        float hnew = sigm(go) * ftanh(cnew);
        h[brow * 512 + j] = hnew;
        hbf[brow * 512 + j] = f2bf(hnew);
        nxt[(size_t)brow * 800 + 288 + j] = f2bf(cnew);
      }
    }
    arrive_wait(bar, ++ep);

    // ---- phase B: head GEMM (blocks 0..39) ----
    if (bid < 40) {
      int mi2 = bid / 5, ni = bid - mi2 * 5;
      int m02 = mi2 * 64, n02 = ni * 64;
      int wm2 = (wid >> 1) * 32, wn2 = (wid & 1) * 32, wnh2 = wid & 1;
      const unsigned short* A0 = hbf + (size_t)(m02 + wm2 + r) * 512 + q * 8;
      const unsigned short* A1 = A0 + 16 * 512;
      const unsigned short* B0 = Wk2T_sw + (size_t)ni * 16384 + wnh2 * 1024 + l * 8;
      uint4 a0p[2], a1p[2], b0p[2], b1p[2];
      a0p[0] = *reinterpret_cast<const uint4*>(A0);
      a1p[0] = *reinterpret_cast<const uint4*>(A1);
      b0p[0] = *reinterpret_cast<const uint4*>(B0);
      b1p[0] = *reinterpret_cast<const uint4*>(B0 + 512);
      a0p[1] = *reinterpret_cast<const uint4*>(A0 + 32);
      a1p[1] = *reinterpret_cast<const uint4*>(A1 + 32);
      b0p[1] = *reinterpret_cast<const uint4*>(B0 + 2048);
      b1p[1] = *reinterpret_cast<const uint4*>(B0 + 2048 + 512);
      f32x4 acc2[2][2] = {};
#pragma unroll
      for (int kk = 0; kk < 16; ++kk) {
        short8 a0 = as_s8(a0p[kk & 1]), a1 = as_s8(a1p[kk & 1]);
        short8 b0 = as_s8(b0p[kk & 1]), b1 = as_s8(b1p[kk & 1]);
        if (kk + 2 < 16) {
          a0p[kk & 1] = *reinterpret_cast<const uint4*>(A0 + (kk + 2) * 32);
          a1p[kk & 1] = *reinterpret_cast<const uint4*>(A1 + (kk + 2) * 32);
          b0p[kk & 1] = *reinterpret_cast<const uint4*>(B0 + (kk + 2) * 2048);
          b1p[kk & 1] = *reinterpret_cast<const uint4*>(B0 + (kk + 2) * 2048 + 512);
        }
        acc2[0][0] = __builtin_amdgcn_mfma_f32_16x16x32_bf16(a0, b0, acc2[0][0], 0, 0, 0);
        acc2[0][1] = __builtin_amdgcn_mfma_f32_16x16x32_bf16(a0, b1, acc2[0][1], 0, 0, 0);
        acc2[1][0] = __builtin_amdgcn_mfma_f32_16x16x32_bf16(a1, b0, acc2[1][0], 0, 0, 0);
        acc2[1][1] = __builtin_amdgcn_mfma_f32_16x16x32_bf16(a1, b1, acc2[1][1], 0, 0, 0);
      }
#pragma unroll
      for (int mt = 0; mt < 2; ++mt)
#pragma unroll
        for (int nt = 0; nt < 2; ++nt)
#pragma unroll
          for (int e = 0; e < 4; ++e) {
            int row = m02 + wm2 + mt * 16 + q * 4 + e;
            int np = n02 + wn2 + nt * 16 + r;
            float v = acc2[mt][nt][e] + bias2[np];
            if (np < 256) Mk[((size_t)row * 33 + t) * 256 + np] = f2bf(fmaxf(v, 0.f));
            else if (np >= 257 && np < 261) logits[row * 4 + (np - 257)] = v;
          }
    }
    // ---- phase B: attention read for batch b = bid ----
    if (t > 0 && t < 32) {
      int b = bid;
      float s = h[b * 512 + tid] * Wg[tid] + h[b * 512 + 256 + tid] * Wg[256 + tid];
#pragma unroll
      for (int off = 1; off < 64; off <<= 1) s += __shfl_xor(s, off);
      if ((tid & 63) == 0) red4[tid >> 6] = s;
      if (tid < t) wkS[tid] = wk_tbl[((size_t)b * 33 + t) * 33 + tid];
      __syncthreads();
      float g = sigm(red4[0] + red4[1] + red4[2] + red4[3] + bg[0]);
      float acc = 0.f;
      for (int n = 0; n < t; ++n) acc += wkS[n] * bf2f(Mk[((size_t)b * 33 + n) * 256 + tid]);
      nxt[(size_t)b * 800 + tid] = f2bf(g * acc);
      if (tid == 0) nxt[(size_t)b * 800 + 256] = f2bf(g * wck_tbl[b * 33 + t]);
      __syncthreads();
    }
    arrive_wait(bar, ++ep);
  }

  // ---- softmax epilogue (block 0) ----
  if (bid == 0) {
    for (int r2 = tid; r2 < 512; r2 += 256) {
      float a = logits[r2 * 4], b = logits[r2 * 4 + 1], c = logits[r2 * 4 + 2], d = logits[r2 * 4 + 3];
      float m = fmaxf(fmaxf(a, b), fmaxf(c, d));
      float ea = __expf(a - m), eb = __expf(b - m), ec = __expf(c - m), ed = __expf(d - m);
      float s = ea + eb + ec + ed;
      out[r2 * 4] = ea / s; out[r2 * 4 + 1] = eb / s;
      out[r2 * 4 + 2] = ec / s; out[r2 * 4 + 3] = ed / s;
    }
  }
}

extern "C" void kernel_launch(void* const* d_in, const int* in_sizes, int n_in,
                              void* d_out, int out_size, void* d_ws, size_t ws_size,
                              hipStream_t stream) {
  const float* x_seq = (const float*)d_in[0];
  const float* W_enc = (const float*)d_in[1];
  const float* b_enc = (const float*)d_in[2];
  const float* W_lstm = (const float*)d_in[3];
  const float* U_lstm = (const float*)d_in[4];
  const float* b_lstm = (const float*)d_in[5];
  const float* W_key = (const float*)d_in[6];
  const float* b_key = (const float*)d_in[7];
  const float* W_g = (const float*)d_in[8];
  const float* b_g = (const float*)d_in[9];
  const float* W_y = (const float*)d_in[10];
  const float* b_y = (const float*)d_in[11];
  const float* gamma = (const float*)d_in[12];
  const float* beta = (const float*)d_in[13];
  const float* cg = (const float*)d_in[14];
  const float* cb = (const float*)d_in[15];

  char* p = (char*)d_ws;
  auto alloc = [&](size_t bytes) {
    char* r = p;
    p += (bytes + 255) & ~(size_t)255;
    return r;
  };
  float* zbuf = (float*)alloc((size_t)16384 * 128 * 4);
  float* z_full = (float*)alloc((size_t)512 * 33 * 128 * 4);
  unsigned short* WcombT_sw = (unsigned short*)alloc((size_t)2048 * 800 * 2);
  unsigned short* WencT = (unsigned short*)alloc((size_t)128 * 1024 * 2);
  unsigned short* Wk2T_sw = (unsigned short*)alloc((size_t)81920 * 2);
  float* bias2 = (float*)alloc(320 * 4);
  unsigned short* xinA = (unsigned short*)alloc((size_t)512 * 800 * 2);
  unsigned short* xinB = (unsigned short*)alloc((size_t)512 * 800 * 2);
  float* h = (float*)alloc((size_t)512 * 512 * 4);
  unsigned short* hbf = (unsigned short*)alloc((size_t)512 * 512 * 2);
  unsigned short* Mk = (unsigned short*)alloc((size_t)512 * 33 * 256 * 2);
  float* logits = (float*)alloc((size_t)512 * 4 * 4);
  float* wk_tbl = (float*)alloc((size_t)512 * 33 * 33 * 4);
  float* wck_tbl = (float*)alloc((size_t)512 * 33 * 4);
  int* bar = (int*)alloc(1024 * 4);

  const int prep_total = 2048 * 800 + 81920 + 128 * 1024 + 320 + 2 * 512 * 800 + 512 * 512 + 512 * 128 + 1024;
  k_prep<<<(prep_total + 255) / 256, 256, 0, stream>>>(
      W_lstm, U_lstm, W_enc, W_key, W_g, W_y, b_key, b_g, b_y,
      WcombT_sw, Wk2T_sw, WencT, bias2, xinA, xinB, h, z_full, bar);
  k_enc<<<256, 256, 0, stream>>>(x_seq, WencT, b_enc, zbuf);
  k_ln<<<256, 256, 0, stream>>>(zbuf, gamma, beta, z_full);
  k_coop<<<NBLK, 256, 0, stream>>>(WcombT_sw, Wk2T_sw, bias2, b_lstm, z_full,
                                   cg, cb, W_g, b_g, xinA, xinB, h, hbf, Mk,
                                   logits, wk_tbl, wck_tbl, (float*)d_out, bar);
}

// Round 5
// 1629.371 us; speedup vs baseline: 4.7812x; 2.4115x over previous
//
#include <hip/hip_runtime.h>

typedef __attribute__((ext_vector_type(8))) short short8;
typedef __attribute__((ext_vector_type(4))) float f32x4;
typedef __attribute__((ext_vector_type(8))) unsigned short ushort8;
typedef unsigned long long ull;

__device__ __forceinline__ unsigned short f2bf(float f) {
  union { float f; unsigned u; } v; v.f = f;
  unsigned u = v.u;
  u += 0x7fffu + ((u >> 16) & 1u);
  return (unsigned short)(u >> 16);
}
__device__ __forceinline__ float sigm(float x) { return 1.f / (1.f + __expf(-x)); }
__device__ __forceinline__ float ftanh(float x) { return 1.f - 2.f / (__expf(2.f * x) + 1.f); }
__device__ __forceinline__ ull ald8(const void* p) {
  return __hip_atomic_load((const ull*)p, __ATOMIC_RELAXED, __HIP_MEMORY_SCOPE_AGENT);
}
__device__ __forceinline__ void ast8(void* p, ull v) {
  __hip_atomic_store((ull*)p, v, __ATOMIC_RELAXED, __HIP_MEMORY_SCOPE_AGENT);
}
__device__ __forceinline__ float aldf(const float* p) {
  return __hip_atomic_load(p, __ATOMIC_RELAXED, __HIP_MEMORY_SCOPE_AGENT);
}
__device__ __forceinline__ void astf(float* p, float v) {
  __hip_atomic_store(p, v, __ATOMIC_RELAXED, __HIP_MEMORY_SCOPE_AGENT);
}
__device__ __forceinline__ short8 mk8(ull lo, ull hi) {
  union { ull u[2]; short8 s; } x; x.u[0] = lo; x.u[1] = hi; return x.s;
}
__device__ __forceinline__ ull pkf(float a, float b) {
  union { float f[2]; ull u; } x; x.f[0] = a; x.f[1] = b; return x.u;
}

#define LSTR 40
#define NBLK 512
#define SPIN_CAP 50000000L

// ---------------------------------------------------------------------------
// Prep: bf16 swizzled weights (same layouts as r3/r4), zero state + barrier.
// ---------------------------------------------------------------------------
__global__ void k_prep(const float* __restrict__ W_lstm, const float* __restrict__ U_lstm,
                       const float* __restrict__ W_enc, const float* __restrict__ W_key,
                       const float* __restrict__ W_g, const float* __restrict__ W_y,
                       const float* __restrict__ b_key, const float* __restrict__ b_g,
                       const float* __restrict__ b_y,
                       unsigned short* __restrict__ WcombT_sw, unsigned short* __restrict__ Wk2T_sw,
                       unsigned short* __restrict__ WencT, float* __restrict__ bias2,
                       unsigned short* __restrict__ xinA, unsigned short* __restrict__ xinB,
                       float* __restrict__ h, float* __restrict__ z_full, int* __restrict__ bar) {
  const int N1 = 2048 * 800, N2 = 81920, N3 = 128 * 1024, N4 = 320,
            N5 = 512 * 800, N7 = 512 * 512, N8 = 512 * 128;
  int i = blockIdx.x * 256 + threadIdx.x;
  if (i < N1) {
    int nn = i / 25600, rem = i - nn * 25600;
    int kk = rem >> 10, rem2 = rem & 1023;
    int wnh = rem2 >> 9, l = (rem2 >> 3) & 63, e = rem2 & 7;
    int np = nn * 32 + wnh * 16 + (l & 15);
    int k = kk * 32 + (l >> 4) * 8 + e;
    int j = np >> 2, gate = np & 3, n = gate * 512 + j;
    float v = 0.f;
    if (k < 257) v = W_lstm[k * 2048 + n];
    else if (k >= 288) v = U_lstm[(k - 288) * 2048 + n];
    WcombT_sw[i] = f2bf(v);
    return;
  }
  i -= N1;
  if (i < N2) {
    int ni = i / 16384, rem = i - ni * 16384;
    int kk = rem >> 11, rem2 = rem & 2047;
    int wnh = rem2 >> 10, nt = (rem2 >> 9) & 1, l = (rem2 >> 3) & 63, e = rem2 & 7;
    int n = ni * 64 + wnh * 32 + nt * 16 + (l & 15);
    int k = kk * 32 + (l >> 4) * 8 + e;
    float v = 0.f;
    if (n < 256) v = W_key[k * 256 + n];
    else if (n == 256) v = W_g[k];
    else if (n < 261) v = W_y[k * 4 + (n - 257)];
    Wk2T_sw[i] = f2bf(v);
    return;
  }
  i -= N2;
  if (i < N3) {
    int n = i / 1024, k = i - n * 1024;
    WencT[i] = f2bf(W_enc[k * 128 + n]);
    return;
  }
  i -= N3;
  if (i < N4) {
    float v = (i < 256) ? b_key[i] : (i == 256 ? b_g[0] : (i < 261 ? b_y[i - 257] : 0.f));
    bias2[i] = v;
    return;
  }
  i -= N4;
  if (i < N5) { xinA[i] = 0; return; }
  i -= N5;
  if (i < N5) { xinB[i] = 0; return; }
  i -= N5;
  if (i < N7) { h[i] = 0.f; return; }
  i -= N7;
  if (i < N8) {
    int b = i >> 7, z = i & 127;
    z_full[(b * 33 + 32) * 128 + z] = 0.f;
    return;
  }
  i -= N8;
  if (i < 1024) bar[i] = 0;
}

// ---------------------------------------------------------------------------
// Encoder GEMM (unchanged, known-good ~41 us).
// ---------------------------------------------------------------------------
__global__ __launch_bounds__(256) void k_enc(const float* __restrict__ x,
                                             const unsigned short* __restrict__ WencT,
                                             const float* __restrict__ b_enc,
                                             float* __restrict__ zbuf) {
  __shared__ __align__(16) unsigned short As[2][64 * LSTR];
  __shared__ __align__(16) unsigned short Bs[2][128 * LSTR];
  int tid = threadIdx.x;
  int m0 = blockIdx.x * 64;
  int lane = tid & 63, wid = tid >> 6;
  int wm = (wid >> 1) * 32, wn = (wid & 1) * 64;
  int q = lane >> 4, r = lane & 15;
  int ldrowA = tid >> 2, ldcA = (tid & 3) * 8;
  int ldrowB = tid >> 1, ldcB = (tid & 1) * 16;
  const float4* Ag = reinterpret_cast<const float4*>(x + (size_t)(m0 + ldrowA) * 1024);
  const uint4* Bg = reinterpret_cast<const uint4*>(WencT + (size_t)ldrowB * 1024);
  float4 ra0 = Ag[ldcA >> 2], ra1 = Ag[(ldcA >> 2) + 1];
  uint4 rb0 = Bg[ldcB >> 3], rb1 = Bg[(ldcB >> 3) + 1];
  f32x4 acc[2][4] = {};
  int s = 0;
  {
    ushort8 t8;
    t8[0] = f2bf(ra0.x); t8[1] = f2bf(ra0.y); t8[2] = f2bf(ra0.z); t8[3] = f2bf(ra0.w);
    t8[4] = f2bf(ra1.x); t8[5] = f2bf(ra1.y); t8[6] = f2bf(ra1.z); t8[7] = f2bf(ra1.w);
    *reinterpret_cast<ushort8*>(&As[0][ldrowA * LSTR + ldcA]) = t8;
    *reinterpret_cast<uint4*>(&Bs[0][ldrowB * LSTR + ldcB]) = rb0;
    *reinterpret_cast<uint4*>(&Bs[0][ldrowB * LSTR + ldcB + 8]) = rb1;
  }
  __syncthreads();
  for (int kk = 0; kk < 32; ++kk) {
    if (kk < 31) {
      int k0 = (kk + 1) * 32;
      ra0 = Ag[(k0 + ldcA) >> 2]; ra1 = Ag[((k0 + ldcA) >> 2) + 1];
      rb0 = Bg[(k0 + ldcB) >> 3]; rb1 = Bg[((k0 + ldcB) >> 3) + 1];
    }
    short8 a0 = *reinterpret_cast<const short8*>(&As[s][(wm + r) * LSTR + q * 8]);
    short8 a1 = *reinterpret_cast<const short8*>(&As[s][(wm + 16 + r) * LSTR + q * 8]);
#pragma unroll
    for (int nt = 0; nt < 4; ++nt) {
      short8 b0 = *reinterpret_cast<const short8*>(&Bs[s][(wn + nt * 16 + r) * LSTR + q * 8]);
      acc[0][nt] = __builtin_amdgcn_mfma_f32_16x16x32_bf16(a0, b0, acc[0][nt], 0, 0, 0);
      acc[1][nt] = __builtin_amdgcn_mfma_f32_16x16x32_bf16(a1, b0, acc[1][nt], 0, 0, 0);
    }
    if (kk < 31) {
      ushort8 t8;
      t8[0] = f2bf(ra0.x); t8[1] = f2bf(ra0.y); t8[2] = f2bf(ra0.z); t8[3] = f2bf(ra0.w);
      t8[4] = f2bf(ra1.x); t8[5] = f2bf(ra1.y); t8[6] = f2bf(ra1.z); t8[7] = f2bf(ra1.w);
      *reinterpret_cast<ushort8*>(&As[s ^ 1][ldrowA * LSTR + ldcA]) = t8;
      *reinterpret_cast<uint4*>(&Bs[s ^ 1][ldrowB * LSTR + ldcB]) = rb0;
      *reinterpret_cast<uint4*>(&Bs[s ^ 1][ldrowB * LSTR + ldcB + 8]) = rb1;
      s ^= 1;
    }
    __syncthreads();
  }
#pragma unroll
  for (int mt = 0; mt < 2; ++mt)
#pragma unroll
    for (int nt = 0; nt < 4; ++nt)
#pragma unroll
      for (int e = 0; e < 4; ++e) {
        int row = m0 + wm + mt * 16 + q * 4 + e;
        int col = wn + nt * 16 + r;
        zbuf[(size_t)row * 128 + col] = fmaxf(acc[mt][nt][e] + b_enc[col], 0.f);
      }
}

// ---------------------------------------------------------------------------
// LayerNorm over batch axis (unchanged).
// ---------------------------------------------------------------------------
__global__ __launch_bounds__(256) void k_ln(const float* __restrict__ zbuf,
                                            const float* __restrict__ gamma,
                                            const float* __restrict__ beta,
                                            float* __restrict__ z_full) {
  int bid = blockIdx.x;
  int tstep = bid >> 3;
  int z0 = (bid & 7) * 16;
  int tid = threadIdx.x;
  int zl = tid & 15, bg = tid >> 4;
  __shared__ float ps[256], qs[256];
  __shared__ float muS[16], rsS[16];
  float s = 0.f, ss = 0.f;
  for (int ii = 0; ii < 32; ++ii) {
    int b = bg * 32 + ii;
    float v = zbuf[(size_t)(b * 32 + tstep) * 128 + z0 + zl];
    s += v; ss += v * v;
  }
  ps[tid] = s; qs[tid] = ss;
  __syncthreads();
  if (tid < 16) {
    float S = 0.f, Q = 0.f;
    for (int g2 = 0; g2 < 16; ++g2) { S += ps[g2 * 16 + tid]; Q += qs[g2 * 16 + tid]; }
    float mu = S / 512.f;
    float var = Q / 512.f - mu * mu;
    muS[tid] = mu;
    rsS[tid] = rsqrtf(var + 1e-8f);
  }
  __syncthreads();
  float ga = gamma[z0 + zl], be = beta[z0 + zl];
  float mu = muS[zl], rs = rsS[zl];
  for (int ii = 0; ii < 32; ++ii) {
    int b = bg * 32 + ii;
    float v = zbuf[(size_t)(b * 32 + tstep) * 128 + z0 + zl];
    z_full[(size_t)(b * 33 + tstep) * 128 + z0 + zl] = (v - mu) * rs * ga + be;
  }
}

// ---------------------------------------------------------------------------
// Group barrier: 8 independent 64-block domains. Relaxed agent atomics only —
// NO fences, NO RMW, NO cache maintenance. Data moved via sc1 atomics is
// already at the coherence point; we only need vmcnt drain before the flag.
// bar[g*64+nn] arrival flags, bar[512+g] release.
// ---------------------------------------------------------------------------
__device__ __forceinline__ void grp_bar(int* __restrict__ bar, int g, int nn, int ep) {
  __builtin_amdgcn_s_waitcnt(0);   // this wave's stores complete (sc1 -> visible)
  __syncthreads();                 // all waves drained
  int tid = threadIdx.x;
  if (tid == 0)
    __hip_atomic_store(&bar[g * 64 + nn], ep, __ATOMIC_RELAXED, __HIP_MEMORY_SCOPE_AGENT);
  if (nn == 0) {
    if (tid < 64) {
      long sp = 0;
      while (__hip_atomic_load(&bar[g * 64 + tid], __ATOMIC_RELAXED, __HIP_MEMORY_SCOPE_AGENT) < ep) {
        __builtin_amdgcn_s_sleep(1);
        if (++sp > SPIN_CAP) break;
      }
    }
    __syncthreads();
    if (tid == 0)
      __hip_atomic_store(&bar[512 + g], ep, __ATOMIC_RELAXED, __HIP_MEMORY_SCOPE_AGENT);
  }
  if (tid == 0) {
    long sp = 0;
    while (__hip_atomic_load(&bar[512 + g], __ATOMIC_RELAXED, __HIP_MEMORY_SCOPE_AGENT) < ep) {
      __builtin_amdgcn_s_sleep(1);
      if (++sp > SPIN_CAP) break;
    }
  }
  __syncthreads();
}

// ---------------------------------------------------------------------------
// Persistent recurrence kernel. 512 blocks; group g = bid>>6 owns batch rows
// 64g..64g+63; nn = bid&63 owns n'-slice nn*32. All cross-block traffic via
// relaxed agent atomics (IF$-coherent). Head GEMM: nn 0..4 of each group.
// Softmax fused into nn==4 block at t==32.
// ---------------------------------------------------------------------------
__global__ __launch_bounds__(256, 2) void k_coop(
    const unsigned short* __restrict__ WcombT_sw, const unsigned short* __restrict__ Wk2T_sw,
    const float* __restrict__ bias2, const float* __restrict__ b_lstm,
    const float* __restrict__ z_full, const float* __restrict__ cgain,
    const float* __restrict__ cbias, const float* __restrict__ Wg,
    const float* __restrict__ bg,
    unsigned short* xinA, unsigned short* xinB,
    float* h, unsigned short* hbf, float* Mk,
    float* out, int* bar) {
  __shared__ __align__(16) unsigned short Bf[25600];  // persistent gates B-tile 51.2 KB
  __shared__ __align__(16) char ovl[21504];           // attnpre / Cs / phaseB scratch
  __shared__ float wkL[33 * 33];
  __shared__ float wckL[33];
  int tid = threadIdx.x;
  int bid = blockIdx.x;
  int l = tid & 63, wid = tid >> 6;
  int q = l >> 4, r = l & 15;
  int g = bid >> 6, nn = bid & 63;
  int m0 = g * 64;
  int ep = 0;

  // --- persistent gates B tile ---
  {
    const uint2* Bsrc = reinterpret_cast<const uint2*>(WcombT_sw + (size_t)nn * 25600);
    uint2* Bdst = reinterpret_cast<uint2*>(Bf);
#pragma unroll
    for (int i = 0; i < 25; ++i) Bdst[tid + i * 256] = Bsrc[tid + i * 256];
  }

  // --- attention precompute for batch b = bid (block-local, wk/wck -> LDS) ---
  {
    float* zs = (float*)ovl;
    float* sim = (float*)(ovl + 16896);
    const float* zb = z_full + (size_t)bid * 4224;
    for (int i = tid; i < 4224; i += 256) zs[i] = zb[i];
    __syncthreads();
    for (int p = tid; p < 1089; p += 256) {
      int t = p / 33, n = p - t * 33;
      float s = 0.f;
      if (n < t) {
#pragma unroll 8
        for (int k2 = 0; k2 < 128; ++k2) s += zs[t * 128 + k2] * zs[n * 128 + k2];
      }
      sim[p] = s;
    }
    __syncthreads();
    if (tid >= 1 && tid < 33) {
      int t = tid;
      float cg = cgain[0], cb2 = cbias[0];
      float m = -3.0e38f;
      for (int n = 0; n < t; ++n) m = fmaxf(m, sim[t * 33 + n]);
      float ssum = 0.f;
      for (int n = 0; n < t; ++n) ssum += __expf(sim[t * 33 + n] - m);
      float inv = 1.f / ssum;
      float wck = 0.f;
      for (int n = 0; n < t; ++n) {
        float wk = __expf(sim[t * 33 + n] - m) * inv;
        wkL[t * 33 + n] = wk;
        float ck = 1.f / (1.f + __expf(-(sim[t * 33 + n] * cg + cb2)));
        wck += wk * ck;
      }
      wckL[t] = wck;
    }
  }
  __syncthreads();

  float* Cs = (float*)ovl;                       // 64*33 f32
  float* red4 = (float*)ovl;                     // 4 f32 (phase B)
  unsigned short* kscr = (unsigned short*)(ovl + 64);  // 260 ushort
  float* lscr = (float*)(ovl + 2048);            // 64*4 f32 (t==32)

  for (int t = 0; t < 33; ++t) {
    unsigned short* cur = (t & 1) ? xinB : xinA;
    unsigned short* nxt = (t & 1) ? xinA : xinB;

    // ---- phase A: gates GEMM (wave = 16 rows x 32 cols, K=800) + cell ----
    {
      const unsigned short* Ap = cur + (size_t)(m0 + wid * 16 + r) * 800 + q * 8;
      ull al[3], ah[3];
      al[0] = ald8(Ap);      ah[0] = ald8(Ap + 4);
      al[1] = ald8(Ap + 32); ah[1] = ald8(Ap + 36);
      al[2] = ald8(Ap + 64); ah[2] = ald8(Ap + 68);
      f32x4 c0 = {}, c1 = {};
#pragma unroll
      for (int kk = 0; kk < 25; ++kk) {
        int s3 = kk % 3;
        short8 a = mk8(al[s3], ah[s3]);
        if (kk + 3 < 25) {
          al[s3] = ald8(Ap + (kk + 3) * 32);
          ah[s3] = ald8(Ap + (kk + 3) * 32 + 4);
        }
        short8 b0 = *reinterpret_cast<const short8*>(&Bf[kk * 1024 + l * 8]);
        short8 b1 = *reinterpret_cast<const short8*>(&Bf[kk * 1024 + 512 + l * 8]);
        c0 = __builtin_amdgcn_mfma_f32_16x16x32_bf16(a, b0, c0, 0, 0, 0);
        c1 = __builtin_amdgcn_mfma_f32_16x16x32_bf16(a, b1, c1, 0, 0, 0);
      }
#pragma unroll
      for (int e = 0; e < 4; ++e) {
        Cs[(wid * 16 + q * 4 + e) * 33 + r] = c0[e];
        Cs[(wid * 16 + q * 4 + e) * 33 + 16 + r] = c1[e];
      }
      __syncthreads();
      // cell: 128 threads x (row, 4-j quad)
      if (tid < 128) {
        int rl = tid >> 1, q4 = tid & 1;
        int brow = m0 + rl;
        int j0 = nn * 8 + q4 * 4;
        float hn[4], cn[4];
#pragma unroll
        for (int jj = 0; jj < 4; ++jj) {
          int lc = (q4 * 4 + jj) * 4;
          int j = j0 + jj;
          float gi = Cs[rl * 33 + lc + 0] + b_lstm[j];
          float gf = Cs[rl * 33 + lc + 1] + b_lstm[512 + j];
          float gg = Cs[rl * 33 + lc + 2] + b_lstm[1024 + j];
          float go = Cs[rl * 33 + lc + 3] + b_lstm[1536 + j];
          float hold = aldf(&h[brow * 512 + j]);
          cn[jj] = sigm(gf) * hold + sigm(gi) * ftanh(gg);
          hn[jj] = sigm(go) * ftanh(cn[jj]);
        }
        astf(&h[brow * 512 + j0 + 0], hn[0]);
        astf(&h[brow * 512 + j0 + 1], hn[1]);
        astf(&h[brow * 512 + j0 + 2], hn[2]);
        astf(&h[brow * 512 + j0 + 3], hn[3]);
        ull hb = (ull)f2bf(hn[0]) | ((ull)f2bf(hn[1]) << 16) |
                 ((ull)f2bf(hn[2]) << 32) | ((ull)f2bf(hn[3]) << 48);
        ast8(&hbf[brow * 512 + j0], hb);
        ull cb8 = (ull)f2bf(cn[0]) | ((ull)f2bf(cn[1]) << 16) |
                  ((ull)f2bf(cn[2]) << 32) | ((ull)f2bf(cn[3]) << 48);
        ast8(&nxt[(size_t)brow * 800 + 288 + j0], cb8);
      }
    }
    grp_bar(bar, g, nn, ++ep);

    // ---- phase B: head GEMM (nn 0..4 of each group) ----
    if (nn < 5) {
      int n02 = nn * 64;
      int wm2 = (wid >> 1) * 32, wn2 = (wid & 1) * 32, wnh2 = wid & 1;
      const unsigned short* A0 = hbf + (size_t)(m0 + wm2 + r) * 512 + q * 8;
      const unsigned short* A1 = A0 + 16 * 512;
      const unsigned short* B0 = Wk2T_sw + (size_t)nn * 16384 + wnh2 * 1024 + l * 8;
      ull a0l[3], a0h[3], a1l[3], a1h[3];
#pragma unroll
      for (int d = 0; d < 3; ++d) {
        a0l[d] = ald8(A0 + d * 32); a0h[d] = ald8(A0 + d * 32 + 4);
        a1l[d] = ald8(A1 + d * 32); a1h[d] = ald8(A1 + d * 32 + 4);
      }
      f32x4 acc2[2][2] = {};
#pragma unroll
      for (int kk = 0; kk < 16; ++kk) {
        int s3 = kk % 3;
        short8 a0 = mk8(a0l[s3], a0h[s3]), a1 = mk8(a1l[s3], a1h[s3]);
        uint4 b0r = *reinterpret_cast<const uint4*>(B0 + kk * 2048);
        uint4 b1r = *reinterpret_cast<const uint4*>(B0 + kk * 2048 + 512);
        if (kk + 3 < 16) {
          a0l[s3] = ald8(A0 + (kk + 3) * 32); a0h[s3] = ald8(A0 + (kk + 3) * 32 + 4);
          a1l[s3] = ald8(A1 + (kk + 3) * 32); a1h[s3] = ald8(A1 + (kk + 3) * 32 + 4);
        }
        union { uint4 u; short8 s; } xb0, xb1; xb0.u = b0r; xb1.u = b1r;
        acc2[0][0] = __builtin_amdgcn_mfma_f32_16x16x32_bf16(a0, xb0.s, acc2[0][0], 0, 0, 0);
        acc2[0][1] = __builtin_amdgcn_mfma_f32_16x16x32_bf16(a0, xb1.s, acc2[0][1], 0, 0, 0);
        acc2[1][0] = __builtin_amdgcn_mfma_f32_16x16x32_bf16(a1, xb0.s, acc2[1][0], 0, 0, 0);
        acc2[1][1] = __builtin_amdgcn_mfma_f32_16x16x32_bf16(a1, xb1.s, acc2[1][1], 0, 0, 0);
      }
#pragma unroll
      for (int mt = 0; mt < 2; ++mt)
#pragma unroll
        for (int nt = 0; nt < 2; ++nt) {
          int np = n02 + wn2 + nt * 16 + r;
          int row0 = m0 + wm2 + mt * 16 + q * 4;
          if (np < 256) {
            float v0 = fmaxf(acc2[mt][nt][0] + bias2[np], 0.f);
            float v1 = fmaxf(acc2[mt][nt][1] + bias2[np], 0.f);
            float v2 = fmaxf(acc2[mt][nt][2] + bias2[np], 0.f);
            float v3 = fmaxf(acc2[mt][nt][3] + bias2[np], 0.f);
            float* mp = Mk + ((size_t)t * 256 + np) * 512 + row0;
            ast8(mp, pkf(v0, v1));
            ast8(mp + 2, pkf(v2, v3));
          } else if (t == 32 && np >= 257 && np < 261) {
#pragma unroll
            for (int e = 0; e < 4; ++e) {
              int rloc = wm2 + mt * 16 + q * 4 + e;
              lscr[rloc * 4 + (np - 257)] = acc2[mt][nt][e] + bias2[np];
            }
          }
        }
    }
    // ---- phase B: attention for batch b = bid ----
    if (t > 0 && t < 32) {
      int b = bid;
      float s = aldf(&h[b * 512 + tid]) * Wg[tid] + aldf(&h[b * 512 + 256 + tid]) * Wg[256 + tid];
#pragma unroll
      for (int off = 1; off < 64; off <<= 1) s += __shfl_xor(s, off);
      if (l == 0) red4[wid] = s;
      if (tid >= 1 && tid <= 3) kscr[256 + tid] = 0;
      __syncthreads();
      float gv = sigm(red4[0] + red4[1] + red4[2] + red4[3] + bg[0]);
      float acc = 0.f;
      for (int n = 0; n < t; ++n)
        acc += wkL[t * 33 + n] * aldf(&Mk[((size_t)n * 256 + tid) * 512 + b]);
      kscr[tid] = f2bf(gv * acc);
      if (tid == 0) kscr[256] = f2bf(gv * wckL[t]);
      __syncthreads();
      if (tid < 65) {
        ull u = (ull)kscr[tid * 4] | ((ull)kscr[tid * 4 + 1] << 16) |
                ((ull)kscr[tid * 4 + 2] << 32) | ((ull)kscr[tid * 4 + 3] << 48);
        ast8(&nxt[(size_t)b * 800 + tid * 4], u);
      }
    }
    // ---- t==32: fused softmax by the logits-owning head block ----
    if (t == 32 && nn == 4) {
      __syncthreads();
      if (tid < 64) {
        float a = lscr[tid * 4], b2 = lscr[tid * 4 + 1], c = lscr[tid * 4 + 2], d = lscr[tid * 4 + 3];
        float m = fmaxf(fmaxf(a, b2), fmaxf(c, d));
        float ea = __expf(a - m), eb = __expf(b2 - m), ec = __expf(c - m), ed = __expf(d - m);
        float sm = ea + eb + ec + ed;
        int row = g * 64 + tid;
        out[row * 4] = ea / sm; out[row * 4 + 1] = eb / sm;
        out[row * 4 + 2] = ec / sm; out[row * 4 + 3] = ed / sm;
      }
    }
    grp_bar(bar, g, nn, ++ep);
  }
}

extern "C" void kernel_launch(void* const* d_in, const int* in_sizes, int n_in,
                              void* d_out, int out_size, void* d_ws, size_t ws_size,
                              hipStream_t stream) {
  const float* x_seq = (const float*)d_in[0];
  const float* W_enc = (const float*)d_in[1];
  const float* b_enc = (const float*)d_in[2];
  const float* W_lstm = (const float*)d_in[3];
  const float* U_lstm = (const float*)d_in[4];
  const float* b_lstm = (const float*)d_in[5];
  const float* W_key = (const float*)d_in[6];
  const float* b_key = (const float*)d_in[7];
  const float* W_g = (const float*)d_in[8];
  const float* b_g = (const float*)d_in[9];
  const float* W_y = (const float*)d_in[10];
  const float* b_y = (const float*)d_in[11];
  const float* gamma = (const float*)d_in[12];
  const float* beta = (const float*)d_in[13];
  const float* cg = (const float*)d_in[14];
  const float* cb = (const float*)d_in[15];

  char* p = (char*)d_ws;
  auto alloc = [&](size_t bytes) {
    char* r = p;
    p += (bytes + 255) & ~(size_t)255;
    return r;
  };
  float* zbuf = (float*)alloc((size_t)16384 * 128 * 4);
  float* z_full = (float*)alloc((size_t)512 * 33 * 128 * 4);
  unsigned short* WcombT_sw = (unsigned short*)alloc((size_t)2048 * 800 * 2);
  unsigned short* WencT = (unsigned short*)alloc((size_t)128 * 1024 * 2);
  unsigned short* Wk2T_sw = (unsigned short*)alloc((size_t)81920 * 2);
  float* bias2 = (float*)alloc(320 * 4);
  unsigned short* xinA = (unsigned short*)alloc((size_t)512 * 800 * 2);
  unsigned short* xinB = (unsigned short*)alloc((size_t)512 * 800 * 2);
  float* h = (float*)alloc((size_t)512 * 512 * 4);
  unsigned short* hbf = (unsigned short*)alloc((size_t)512 * 512 * 2);
  float* Mk = (float*)alloc((size_t)33 * 256 * 512 * 4);
  int* bar = (int*)alloc(1024 * 4);

  const int prep_total = 2048 * 800 + 81920 + 128 * 1024 + 320 + 2 * 512 * 800 + 512 * 512 + 512 * 128 + 1024;
  k_prep<<<(prep_total + 255) / 256, 256, 0, stream>>>(
      W_lstm, U_lstm, W_enc, W_key, W_g, W_y, b_key, b_g, b_y,
      WcombT_sw, Wk2T_sw, WencT, bias2, xinA, xinB, h, z_full, bar);
  k_enc<<<256, 256, 0, stream>>>(x_seq, WencT, b_enc, zbuf);
  k_ln<<<256, 256, 0, stream>>>(zbuf, gamma, beta, z_full);
  k_coop<<<NBLK, 256, 0, stream>>>(WcombT_sw, Wk2T_sw, bias2, b_lstm, z_full,
                                   cg, cb, W_g, b_g, xinA, xinB, h, hbf, Mk,
                                   (float*)d_out, bar);
}